// Round 8
// baseline (522.844 us; speedup 1.0000x reference)
//
#include <hip/hip_runtime.h>
#include <hip/hip_bf16.h>

// Problem constants (fixed by the reference file)
#define DIN   128
#define HID2  64
#define NCLS  10
#define NGRAPH 128
#define SCAN_CHUNK 1024
#define NBLK 1024          // blocks in bhist/partition (must match between them)

typedef __attribute__((ext_vector_type(8))) short bf16x8;
typedef __attribute__((ext_vector_type(4))) float f32x4;

__device__ __forceinline__ void atomAddF(float* p, float v) {
    unsafeAtomicAdd(p, v);
}

// float -> bf16 (round-to-nearest-even), finite inputs
__device__ __forceinline__ unsigned short f2bf(float f) {
    unsigned int u = __float_as_uint(f);
    u += 0x7fffu + ((u >> 16) & 1u);
    return (unsigned short)(u >> 16);
}

// ---------- K0: W12 = lin1_w @ conv1_w ; c1preb = lin1_b @ conv1_w ----------
__global__ __launch_bounds__(128) void k_w12(const float* __restrict__ lw,
                                             const float* __restrict__ lb,
                                             const float* __restrict__ cw,
                                             float* __restrict__ W12,
                                             float* __restrict__ c1preb) {
    int i = blockIdx.x, j = threadIdx.x;
    const float* arow = (i < 128) ? (lw + i * 128) : lb;
    float acc = 0.f;
#pragma unroll 8
    for (int k = 0; k < 128; ++k) acc += arow[k] * cw[k * 128 + j];
    if (i < 128) W12[i * 128 + j] = acc;
    else         c1preb[j] = acc;
}

__global__ __launch_bounds__(256) void k_zeroi(int* p, int n) {
    int i = blockIdx.x * 256 + threadIdx.x;
    if (i < n) p[i] = 0;
}
__global__ __launch_bounds__(256) void k_zero(float* p, int n) {
    int i = blockIdx.x * 256 + threadIdx.x;
    if (i < n) p[i] = 0.0f;
}

// ---------- radix partition of edges by dst region (8 buckets) ----------
// Pass 1: per-(block,bucket) histogram. bh[b*NBLK + blk].
__global__ __launch_bounds__(256) void k_bhist(const int* __restrict__ dst,
                                               int* __restrict__ bh, int E, int N) {
    __shared__ int lh[8];
    if (threadIdx.x < 8) lh[threadIdx.x] = 0;
    __syncthreads();
    const int chunk = (N + 7) / 8;
    for (int e = blockIdx.x * 256 + threadIdx.x; e < E; e += gridDim.x * 256) {
        int d = __builtin_nontemporal_load(dst + e);
        atomicAdd(&lh[d / chunk], 1);
    }
    __syncthreads();
    if (threadIdx.x < 8) bh[threadIdx.x * NBLK + blockIdx.x] = lh[threadIdx.x];
}

// Pass 2: in-place exclusive scan of bh[0..8*NBLK); bh[8*NBLK] = total.
__global__ __launch_bounds__(1024) void k_bscan(int* __restrict__ bh) {
    const int M = 8 * NBLK;          // 8192
    __shared__ int sh[1024];
    const int t = threadIdx.x;
    const int base = t * 8;
    int c[8]; int s = 0;
#pragma unroll
    for (int j = 0; j < 8; ++j) { c[j] = bh[base + j]; s += c[j]; }
    sh[t] = s;
    __syncthreads();
    for (int off = 1; off < 1024; off <<= 1) {
        int u = (t >= off) ? sh[t - off] : 0;
        __syncthreads();
        sh[t] += u;
        __syncthreads();
    }
    int val = sh[t] - s;             // exclusive prefix of this thread's chunk
#pragma unroll
    for (int j = 0; j < 8; ++j) { bh[base + j] = val; val += c[j]; }
    if (t == 1023) bh[M] = sh[1023];
}

// Pass 3: scatter (dst,src) pairs into per-(block,bucket) pre-scanned ranges.
// LDS cursors only -> zero global atomic contention; same edge assignment as k_bhist.
__global__ __launch_bounds__(256) void k_partition(const int* __restrict__ src,
                                                   const int* __restrict__ dst,
                                                   const int* __restrict__ bh,
                                                   int2* __restrict__ pairs, int E, int N) {
    __shared__ int cur[8];
    if (threadIdx.x < 8) cur[threadIdx.x] = bh[threadIdx.x * NBLK + blockIdx.x];
    __syncthreads();
    const int chunk = (N + 7) / 8;
    for (int e = blockIdx.x * 256 + threadIdx.x; e < E; e += gridDim.x * 256) {
        int d = __builtin_nontemporal_load(dst + e);
        int s = __builtin_nontemporal_load(src + e);
        int pos = atomicAdd(&cur[d / chunk], 1);
        pairs[pos] = make_int2(d, s);
    }
}

// Pass 4: XCD-local histogram from bucket slice (cnt slice stays in one L2).
__global__ __launch_bounds__(256) void k_count_local(const int2* __restrict__ pairs,
                                                     const int* __restrict__ bh,
                                                     int* __restrict__ cnt) {
    const int grp = blockIdx.x & 7;
    const int beg = bh[grp * NBLK];
    const int end = bh[(grp + 1) * NBLK];   // grp==7 -> bh[8*NBLK] = E
    const int nb = gridDim.x >> 3;
    const int bi = blockIdx.x >> 3;
    for (int e = beg + bi * 256 + threadIdx.x; e < end; e += nb * 256) {
        atomicAdd(&cnt[pairs[e].x], 1);
    }
}

__global__ __launch_bounds__(256) void k_dis(const int* __restrict__ cnt, float* dis, int n) {
    int i = blockIdx.x * 256 + threadIdx.x;
    if (i < n) dis[i] = rsqrtf((float)(cnt[i] + 1));   // +1 self-loop
}

// --- 3-phase parallel exclusive scan of cnt -> row_start/cursor ---
__global__ __launch_bounds__(256) void k_scan_part(const int* __restrict__ cnt,
                                                   int* __restrict__ part, int n) {
    int base = blockIdx.x * SCAN_CHUNK + threadIdx.x * 4;
    int s = 0;
#pragma unroll
    for (int j = 0; j < 4; ++j) { int i = base + j; if (i < n) s += cnt[i]; }
#pragma unroll
    for (int o = 32; o > 0; o >>= 1) s += __shfl_down(s, o);
    __shared__ int wsum[4];
    if ((threadIdx.x & 63) == 0) wsum[threadIdx.x >> 6] = s;
    __syncthreads();
    if (threadIdx.x == 0) part[blockIdx.x] = wsum[0] + wsum[1] + wsum[2] + wsum[3];
}
__global__ __launch_bounds__(256) void k_scan_mid(int* __restrict__ part,
                                                  int* __restrict__ row_start,
                                                  int B, int n) {
    __shared__ int sh[256];
    int t = threadIdx.x;
    int v = (t < B) ? part[t] : 0;
    sh[t] = v;
    __syncthreads();
    for (int off = 1; off < 256; off <<= 1) {
        int u = (t >= off) ? sh[t - off] : 0;
        __syncthreads();
        sh[t] += u;
        __syncthreads();
    }
    if (t < B) part[t] = sh[t] - v;
    if (t == 255) row_start[n] = sh[255];
}
__global__ __launch_bounds__(256) void k_scan_fin(const int* __restrict__ cnt,
                                                  const int* __restrict__ part,
                                                  int* __restrict__ row_start,
                                                  int* __restrict__ cursor, int n) {
    __shared__ int sh[256];
    int t = threadIdx.x;
    int base = blockIdx.x * SCAN_CHUNK + t * 4;
    int c[4]; int s = 0;
#pragma unroll
    for (int j = 0; j < 4; ++j) { int i = base + j; c[j] = (i < n) ? cnt[i] : 0; s += c[j]; }
    sh[t] = s;
    __syncthreads();
    for (int off = 1; off < 256; off <<= 1) {
        int u = (t >= off) ? sh[t - off] : 0;
        __syncthreads();
        sh[t] += u;
        __syncthreads();
    }
    int excl = part[blockIdx.x] + sh[t] - s;
#pragma unroll
    for (int j = 0; j < 4; ++j) {
        int i = base + j;
        if (i < n) { row_start[i] = excl; cursor[i] = excl; }
        excl += c[j];
    }
}

// Pass 5: XCD-local CSR fill from bucket slice.
__global__ __launch_bounds__(256) void k_fill_local(const int2* __restrict__ pairs,
                                                    const int* __restrict__ bh,
                                                    int* __restrict__ cursor,
                                                    int* __restrict__ col) {
    const int grp = blockIdx.x & 7;
    const int beg = bh[grp * NBLK];
    const int end = bh[(grp + 1) * NBLK];
    const int nb = gridDim.x >> 3;
    const int bi = blockIdx.x >> 3;
    for (int e = beg + bi * 256 + threadIdx.x; e < end; e += nb * 256) {
        int2 p = pairs[e];
        int pos = atomicAdd(&cursor[p.x], 1);
        col[pos] = p.y;
    }
}

// ---------- MFMA bf16 GEMM: out[M x NCOL] = bf16(f(A[M x 128]) @ W[128 x NCOL] + bias) ----------
template <int NCOL, bool MASK>
__global__ __launch_bounds__(256) void k_gemm_mfma(const float* __restrict__ A,
                                                   const float* __restrict__ W,
                                                   const float* __restrict__ bias,
                                                   const float* __restrict__ du,
                                                   unsigned short* __restrict__ out, int M) {
    constexpr int KP = 136;
    __shared__ unsigned short As[64 * KP];
    __shared__ unsigned short Wt[NCOL * KP];

    const int tid = threadIdx.x;
    const int row0 = blockIdx.x * 64;

    for (int f = tid; f < 2048; f += 256) {
        int r = f >> 5, c4 = f & 31;
        int gr = row0 + r;
        float4 v = make_float4(0.f, 0.f, 0.f, 0.f);
        if (gr < M) {
            v = *(const float4*)(A + (size_t)gr * 128 + c4 * 4);
            if (MASK) {
                float4 u = *(const float4*)(du + (size_t)gr * 128 + c4 * 4);
                v.x = (u.x >= 0.5f) ? 2.f * fmaxf(v.x, 0.f) : 0.f;
                v.y = (u.y >= 0.5f) ? 2.f * fmaxf(v.y, 0.f) : 0.f;
                v.z = (u.z >= 0.5f) ? 2.f * fmaxf(v.z, 0.f) : 0.f;
                v.w = (u.w >= 0.5f) ? 2.f * fmaxf(v.w, 0.f) : 0.f;
            }
        }
        ushort4 b;
        b.x = f2bf(v.x); b.y = f2bf(v.y); b.z = f2bf(v.z); b.w = f2bf(v.w);
        *(ushort4*)(&As[r * KP + c4 * 4]) = b;
    }
    for (int f = tid; f < 32 * NCOL; f += 256) {
        int k = f / (NCOL / 4), n4 = f % (NCOL / 4);
        float4 v = *(const float4*)(W + (size_t)k * NCOL + n4 * 4);
        Wt[(n4 * 4 + 0) * KP + k] = f2bf(v.x);
        Wt[(n4 * 4 + 1) * KP + k] = f2bf(v.y);
        Wt[(n4 * 4 + 2) * KP + k] = f2bf(v.z);
        Wt[(n4 * 4 + 3) * KP + k] = f2bf(v.w);
    }
    __syncthreads();

    const int wave = tid >> 6, lane = tid & 63;
    const int quad = lane >> 4, l16 = lane & 15;
    constexpr int CT = (NCOL == 128) ? 2 : 1;
    const int col0 = wave * 16 * CT;

    f32x4 acc[4][CT];
#pragma unroll
    for (int rt = 0; rt < 4; ++rt)
#pragma unroll
        for (int ct = 0; ct < CT; ++ct) acc[rt][ct] = 0.f;

#pragma unroll
    for (int ks = 0; ks < 4; ++ks) {
        const int kbase = ks * 32 + quad * 8;
        bf16x8 bfr[CT];
#pragma unroll
        for (int ct = 0; ct < CT; ++ct)
            bfr[ct] = *(const bf16x8*)(&Wt[(col0 + ct * 16 + l16) * KP + kbase]);
#pragma unroll
        for (int rt = 0; rt < 4; ++rt) {
            bf16x8 afr = *(const bf16x8*)(&As[(rt * 16 + l16) * KP + kbase]);
#pragma unroll
            for (int ct = 0; ct < CT; ++ct)
                acc[rt][ct] = __builtin_amdgcn_mfma_f32_16x16x32_bf16(afr, bfr[ct], acc[rt][ct], 0, 0, 0);
        }
    }

#pragma unroll
    for (int rt = 0; rt < 4; ++rt)
#pragma unroll
        for (int ct = 0; ct < CT; ++ct) {
            const int c = col0 + ct * 16 + l16;
            const float bv = bias ? bias[c] : 0.f;
#pragma unroll
            for (int reg = 0; reg < 4; ++reg) {
                const int gr = row0 + rt * 16 + quad * 4 + reg;
                if (gr < M) out[(size_t)gr * NCOL + c] = f2bf(acc[rt][ct][reg] + bv);
            }
        }
}

// ---------- CSR gather (bf16 input rows, fp32 accumulate+output) ----------
__device__ __forceinline__ void bfacc(uint4 v, float d, float* acc) {
    acc[0] = fmaf(d, __uint_as_float(v.x << 16),        acc[0]);
    acc[1] = fmaf(d, __uint_as_float(v.x & 0xffff0000u), acc[1]);
    acc[2] = fmaf(d, __uint_as_float(v.y << 16),        acc[2]);
    acc[3] = fmaf(d, __uint_as_float(v.y & 0xffff0000u), acc[3]);
    acc[4] = fmaf(d, __uint_as_float(v.z << 16),        acc[4]);
    acc[5] = fmaf(d, __uint_as_float(v.z & 0xffff0000u), acc[5]);
    acc[6] = fmaf(d, __uint_as_float(v.w << 16),        acc[6]);
    acc[7] = fmaf(d, __uint_as_float(v.w & 0xffff0000u), acc[7]);
}

template <int NCOL>
__global__ __launch_bounds__(256) void k_gather(const unsigned short* __restrict__ h,
                                                const int* __restrict__ row_start,
                                                const int* __restrict__ col,
                                                const float* __restrict__ dis,
                                                const float* __restrict__ bias,
                                                float* __restrict__ out, int n) {
    constexpr int LPN = NCOL / 8;
    const int node = (blockIdx.x * 256 + threadIdx.x) / LPN;
    const int l = threadIdx.x % LPN;
    if (node >= n) return;
    const int coff = l * 8;

    const float dn = dis[node];
    float acc[8];
    {
        uint4 v = *(const uint4*)(h + (size_t)node * NCOL + coff);
#pragma unroll
        for (int q = 0; q < 8; ++q) acc[q] = 0.f;
        bfacc(v, dn, acc);
    }

    const int beg = row_start[node], end = row_start[node + 1];
    int j = beg;
    for (; j + 1 < end; j += 2) {
        const int s0 = col[j], s1 = col[j + 1];
        const float d0 = dis[s0], d1 = dis[s1];
        const uint4 v0 = *(const uint4*)(h + (size_t)s0 * NCOL + coff);
        const uint4 v1 = *(const uint4*)(h + (size_t)s1 * NCOL + coff);
        bfacc(v0, d0, acc);
        bfacc(v1, d1, acc);
    }
    if (j < end) {
        const int s0 = col[j];
        const float d0 = dis[s0];
        const uint4 v0 = *(const uint4*)(h + (size_t)s0 * NCOL + coff);
        bfacc(v0, d0, acc);
    }

    float4 r0, r1;
    const float4 b0 = *(const float4*)(bias + coff);
    const float4 b1 = *(const float4*)(bias + coff + 4);
    r0.x = fmaf(dn, acc[0], b0.x); r0.y = fmaf(dn, acc[1], b0.y);
    r0.z = fmaf(dn, acc[2], b0.z); r0.w = fmaf(dn, acc[3], b0.w);
    r1.x = fmaf(dn, acc[4], b1.x); r1.y = fmaf(dn, acc[5], b1.y);
    r1.z = fmaf(dn, acc[6], b1.z); r1.w = fmaf(dn, acc[7], b1.w);
    float* o = out + (size_t)node * NCOL + coff;
    *(float4*)(o) = r0;
    *(float4*)(o + 4) = r1;
}

// ---------- pooling: sorted-batch sequential accumulation, wide grid ----------
__global__ __launch_bounds__(256) void k_pool(const float* __restrict__ h,
                                              const int* __restrict__ batch,
                                              float* __restrict__ sums,
                                              float* __restrict__ cnt,
                                              int n) {
    int gid = (blockIdx.x * 256 + threadIdx.x) / 64;
    int f = threadIdx.x % 64;
    int ngroups = gridDim.x * 4;
    int per = (n + ngroups - 1) / ngroups;
    int start = gid * per;
    int end = min(n, start + per);
    if (start >= end) return;
    int cg = batch[start];
    float acc = 0.f;
    int count = 0;
    for (int i = start; i < end; ++i) {
        int b = batch[i];
        if (b != cg) {
            atomAddF(&sums[cg * 64 + f], acc);
            if (f == 0) atomAddF(&cnt[cg], (float)count);
            acc = 0.f; count = 0; cg = b;
        }
        acc += h[(size_t)i * 64 + f];
        ++count;
    }
    atomAddF(&sums[cg * 64 + f], acc);
    if (f == 0) atomAddF(&cnt[cg], (float)count);
}

// ---------- final ----------
__global__ __launch_bounds__(64) void k_final(const float* __restrict__ sums,
                                              const float* __restrict__ cnt,
                                              const float* __restrict__ w,
                                              const float* __restrict__ b,
                                              float* __restrict__ out) {
    int g = blockIdx.x, f = threadIdx.x;
    float c = fmaxf(cnt[g], 1.0f);
    float p = sums[g * 64 + f] / c;
#pragma unroll
    for (int cls = 0; cls < NCLS; ++cls) {
        float v = p * w[f * 10 + cls];
#pragma unroll
        for (int o = 32; o > 0; o >>= 1) v += __shfl_down(v, o);
        if (f == 0) out[g * 10 + cls] = v + b[cls];
    }
}

extern "C" void kernel_launch(void* const* d_in, const int* in_sizes, int n_in,
                              void* d_out, int out_size, void* d_ws, size_t ws_size,
                              hipStream_t stream) {
    const float* x       = (const float*)d_in[0];
    const int*   ei      = (const int*)d_in[1];
    const int*   batch   = (const int*)d_in[2];
    const float* drop_u  = (const float*)d_in[4];
    const float* lin1_w  = (const float*)d_in[5];
    const float* lin1_b  = (const float*)d_in[6];
    const float* conv1_w = (const float*)d_in[7];
    const float* conv1_b = (const float*)d_in[8];
    const float* conv2_w = (const float*)d_in[9];
    const float* conv2_b = (const float*)d_in[10];
    const float* lin2_w  = (const float*)d_in[11];
    const float* lin2_b  = (const float*)d_in[12];
    float* out = (float*)d_out;

    const int N = in_sizes[0] / DIN;        // 100000
    const int E = in_sizes[1] / 2;          // 1600000
    const int* src = ei;
    const int* dst = ei + E;

    // workspace layout (float units)
    float* ws    = (float*)d_ws;
    float* out1  = ws;                                  // N*128 fp32 (reused as out2: N*64)
    unsigned short* h1b = (unsigned short*)(ws + (size_t)N * 128);  // N*128 bf16 (reused as h2b: N*64)
    float* dis   = ws + (size_t)N * 128 + (size_t)N * 64;           // N
    float* W12   = dis + N;                             // 16384
    float* c1pb  = W12 + 16384;                         // 128
    float* sums  = c1pb + 128;                          // 128*64
    float* cntp  = sums + NGRAPH * 64;                  // 128
    int*   cnt   = (int*)(cntp + NGRAPH);               // N
    int*   row_start = cnt + N;                         // N+1
    int*   cursor    = row_start + N + 1;               // N
    int*   part      = cursor + N;                      // 256
    int*   bh        = part + 256;                      // 8*NBLK+1
    int*   col       = bh + 8 * NBLK + 1;               // E
    int2*  pairs     = (int2*)(col + E);                // E int2 (12.8 MB)
    unsigned short* h2b = h1b;
    float* out2  = out1;

    // fused weight + pre-aggregation bias
    k_w12<<<129, 128, 0, stream>>>(lin1_w, lin1_b, conv1_w, W12, c1pb);

    // radix-partitioned CSR build
    k_zeroi<<<(N + 255) / 256, 256, 0, stream>>>(cnt, N);
    k_bhist<<<NBLK, 256, 0, stream>>>(dst, bh, E, N);
    k_bscan<<<1, 1024, 0, stream>>>(bh);
    k_partition<<<NBLK, 256, 0, stream>>>(src, dst, bh, pairs, E, N);
    k_count_local<<<2048, 256, 0, stream>>>(pairs, bh, cnt);
    k_dis<<<(N + 255) / 256, 256, 0, stream>>>(cnt, dis, N);
    const int scanB = (N + SCAN_CHUNK - 1) / SCAN_CHUNK;
    k_scan_part<<<scanB, 256, 0, stream>>>(cnt, part, N);
    k_scan_mid<<<1, 256, 0, stream>>>(part, row_start, scanB, N);
    k_scan_fin<<<scanB, 256, 0, stream>>>(cnt, part, row_start, cursor, N);
    k_fill_local<<<2048, 256, 0, stream>>>(pairs, bh, cursor, col);

    // h1b = bf16(x @ W12 + c1pb)   (MFMA)
    const int gemmGrid = (N + 63) / 64;
    k_gemm_mfma<128, false><<<gemmGrid, 256, 0, stream>>>(x, W12, c1pb, nullptr, h1b, N);

    // conv1 aggregation: out1 = fp32 gather of bf16 h1b
    k_gather<128><<<((size_t)N * 16 + 255) / 256, 256, 0, stream>>>(h1b, row_start, col, dis, conv1_b, out1, N);

    // h2b = bf16(relu(dropout(out1)) @ conv2_w)   (MFMA)
    k_gemm_mfma<64, true><<<gemmGrid, 256, 0, stream>>>(out1, conv2_w, nullptr, drop_u, h2b, N);

    // conv2 aggregation: out2 = fp32 gather of bf16 h2b
    k_gather<64><<<((size_t)N * 8 + 255) / 256, 256, 0, stream>>>(h2b, row_start, col, dis, conv2_b, out2, N);

    // pooled mean + classifier
    k_zero<<<(NGRAPH * 64 + NGRAPH + 255) / 256, 256, 0, stream>>>(sums, NGRAPH * 64 + NGRAPH);
    k_pool<<<2048, 256, 0, stream>>>(out2, batch, sums, cntp, N);
    k_final<<<NGRAPH, 64, 0, stream>>>(sums, cntp, lin2_w, lin2_b, out);
}

// Round 9
// 409.528 us; speedup vs baseline: 1.2767x; 1.2767x over previous
//
#include <hip/hip_runtime.h>
#include <hip/hip_bf16.h>

// Problem constants (fixed by the reference file)
#define DIN   128
#define HID2  64
#define NCLS  10
#define NGRAPH 128
#define SCAN_CHUNK 1024
#define NBLK 256          // blocks in bhist/partition (edge assignment must match)
#define NBKT_MAX 512      // max buckets (nodes/256)
#define CAP 6144          // LDS src-staging capacity per bucket (mean 4096, +32 sigma)

typedef __attribute__((ext_vector_type(8))) short bf16x8;
typedef __attribute__((ext_vector_type(4))) float f32x4;

__device__ __forceinline__ void atomAddF(float* p, float v) {
    unsafeAtomicAdd(p, v);
}

// float -> bf16 (round-to-nearest-even), finite inputs
__device__ __forceinline__ unsigned short f2bf(float f) {
    unsigned int u = __float_as_uint(f);
    u += 0x7fffu + ((u >> 16) & 1u);
    return (unsigned short)(u >> 16);
}

// ---------- K0: W12 = lin1_w @ conv1_w ; c1preb = lin1_b @ conv1_w ----------
__global__ __launch_bounds__(128) void k_w12(const float* __restrict__ lw,
                                             const float* __restrict__ lb,
                                             const float* __restrict__ cw,
                                             float* __restrict__ W12,
                                             float* __restrict__ c1preb) {
    int i = blockIdx.x, j = threadIdx.x;
    const float* arow = (i < 128) ? (lw + i * 128) : lb;
    float acc = 0.f;
#pragma unroll 8
    for (int k = 0; k < 128; ++k) acc += arow[k] * cw[k * 128 + j];
    if (i < 128) W12[i * 128 + j] = acc;
    else         c1preb[j] = acc;
}

__global__ __launch_bounds__(256) void k_zero(float* p, int n) {
    int i = blockIdx.x * 256 + threadIdx.x;
    if (i < n) p[i] = 0.0f;
}

// ---------- radix CSR build: bucket = dst >> 8 (256 nodes/bucket) ----------
// Pass 1: per-(bucket,block) histogram. bh[bkt*NBLK + blk].
__global__ __launch_bounds__(256) void k_bhist(const int* __restrict__ dst,
                                               int* __restrict__ bh, int E, int nbkt) {
    __shared__ int lh[NBKT_MAX];
    for (int i = threadIdx.x; i < nbkt; i += 256) lh[i] = 0;
    __syncthreads();
    for (int e = blockIdx.x * 256 + threadIdx.x; e < E; e += NBLK * 256)
        atomicAdd(&lh[__builtin_nontemporal_load(dst + e) >> 8], 1);
    __syncthreads();
    for (int i = threadIdx.x; i < nbkt; i += 256) bh[i * NBLK + blockIdx.x] = lh[i];
}

// --- 3-phase parallel exclusive scan (generic length; used on bh in-place) ---
__global__ __launch_bounds__(256) void k_scan_part(const int* __restrict__ cnt,
                                                   int* __restrict__ part, int n) {
    int base = blockIdx.x * SCAN_CHUNK + threadIdx.x * 4;
    int s = 0;
#pragma unroll
    for (int j = 0; j < 4; ++j) { int i = base + j; if (i < n) s += cnt[i]; }
#pragma unroll
    for (int o = 32; o > 0; o >>= 1) s += __shfl_down(s, o);
    __shared__ int wsum[4];
    if ((threadIdx.x & 63) == 0) wsum[threadIdx.x >> 6] = s;
    __syncthreads();
    if (threadIdx.x == 0) part[blockIdx.x] = wsum[0] + wsum[1] + wsum[2] + wsum[3];
}
__global__ __launch_bounds__(256) void k_scan_mid(int* __restrict__ part,
                                                  int* __restrict__ total_out,
                                                  int B, int n) {
    __shared__ int sh[256];
    int t = threadIdx.x;
    int v = (t < B) ? part[t] : 0;
    sh[t] = v;
    __syncthreads();
    for (int off = 1; off < 256; off <<= 1) {
        int u = (t >= off) ? sh[t - off] : 0;
        __syncthreads();
        sh[t] += u;
        __syncthreads();
    }
    if (t < B) part[t] = sh[t] - v;
    if (t == 255) total_out[n] = sh[255];
}
// in-place-safe (out may alias cnt: all reads precede a barrier before writes)
__global__ __launch_bounds__(256) void k_scan_fin2(const int* cnt,
                                                   const int* __restrict__ part,
                                                   int* out, int n) {
    __shared__ int sh[256];
    int t = threadIdx.x;
    int base = blockIdx.x * SCAN_CHUNK + t * 4;
    int c[4]; int s = 0;
#pragma unroll
    for (int j = 0; j < 4; ++j) { int i = base + j; c[j] = (i < n) ? cnt[i] : 0; s += c[j]; }
    sh[t] = s;
    __syncthreads();
    for (int off = 1; off < 256; off <<= 1) {
        int u = (t >= off) ? sh[t - off] : 0;
        __syncthreads();
        sh[t] += u;
        __syncthreads();
    }
    int excl = part[blockIdx.x] + sh[t] - s;
#pragma unroll
    for (int j = 0; j < 4; ++j) {
        int i = base + j;
        if (i < n) out[i] = excl;
        excl += c[j];
    }
}

// Pass 2: scatter (dst,src) pairs into pre-scanned per-(bucket,block) ranges.
// LDS cursors, sequential writes within each private range -> no global contention.
__global__ __launch_bounds__(256) void k_partition(const int* __restrict__ src,
                                                   const int* __restrict__ dst,
                                                   const int* __restrict__ bh,
                                                   int2* __restrict__ pairs, int E, int nbkt) {
    __shared__ int cur[NBKT_MAX];
    for (int i = threadIdx.x; i < nbkt; i += 256) cur[i] = bh[i * NBLK + blockIdx.x];
    __syncthreads();
    for (int e = blockIdx.x * 256 + threadIdx.x; e < E; e += NBLK * 256) {
        int d = __builtin_nontemporal_load(dst + e);
        int s = __builtin_nontemporal_load(src + e);
        int pos = atomicAdd(&cur[d >> 8], 1);
        pairs[pos] = make_int2(d, s);
    }
}

// Pass 3: one block per bucket. In-LDS degree count + scan + scatter, then
// coalesced single-touch streams: row_start, dis, col. No global atomics.
__global__ __launch_bounds__(256) void k_csr_local(const int2* __restrict__ pairs,
                                                   const int* __restrict__ bh,
                                                   int* __restrict__ row_start,
                                                   float* __restrict__ dis,
                                                   int* __restrict__ col,
                                                   int N) {
    __shared__ int cntL[256], scanL[256], curL[256];
    __shared__ int srcbuf[CAP];
    const int tid = threadIdx.x;
    const int lo = blockIdx.x << 8;
    const int bstart = bh[blockIdx.x * NBLK];
    const int bend = bh[(blockIdx.x + 1) * NBLK];   // last bucket: bh[nbkt*NBLK] == E
    const int nE = bend - bstart;

    cntL[tid] = 0;
    __syncthreads();
    for (int e = bstart + tid; e < bend; e += 256)
        atomicAdd(&cntL[pairs[e].x & 255], 1);
    __syncthreads();
    const int deg = cntL[tid];
    scanL[tid] = deg;
    __syncthreads();
    for (int off = 1; off < 256; off <<= 1) {
        int u = (tid >= off) ? scanL[tid - off] : 0;
        __syncthreads();
        scanL[tid] += u;
        __syncthreads();
    }
    const int excl = scanL[tid] - deg;
    curL[tid] = excl;
    const int node = lo + tid;
    if (node < N) {
        row_start[node] = bstart + excl;
        dis[node] = rsqrtf((float)(deg + 1));   // +1 self-loop
    } else if (node == N) {
        row_start[N] = bend;                    // == E (only last bucket reaches here)
    }
    __syncthreads();
    if (nE <= CAP) {
        for (int e = bstart + tid; e < bend; e += 256) {
            int2 p = pairs[e];
            int pos = atomicAdd(&curL[p.x & 255], 1);
            srcbuf[pos] = p.y;
        }
        __syncthreads();
        for (int i = tid; i < nE; i += 256)
            col[bstart + i] = srcbuf[i];
    } else {  // overflow fallback (statistically never for random graphs)
        for (int e = bstart + tid; e < bend; e += 256) {
            int2 p = pairs[e];
            int pos = atomicAdd(&curL[p.x & 255], 1);
            col[bstart + pos] = p.y;
        }
    }
}

// ---------- MFMA bf16 GEMM: out[M x NCOL] = bf16(f(A[M x 128]) @ W[128 x NCOL] + bias) ----------
template <int NCOL, bool MASK>
__global__ __launch_bounds__(256) void k_gemm_mfma(const float* __restrict__ A,
                                                   const float* __restrict__ W,
                                                   const float* __restrict__ bias,
                                                   const float* __restrict__ du,
                                                   unsigned short* __restrict__ out, int M) {
    constexpr int KP = 136;
    __shared__ unsigned short As[64 * KP];
    __shared__ unsigned short Wt[NCOL * KP];

    const int tid = threadIdx.x;
    const int row0 = blockIdx.x * 64;

    for (int f = tid; f < 2048; f += 256) {
        int r = f >> 5, c4 = f & 31;
        int gr = row0 + r;
        float4 v = make_float4(0.f, 0.f, 0.f, 0.f);
        if (gr < M) {
            v = *(const float4*)(A + (size_t)gr * 128 + c4 * 4);
            if (MASK) {
                float4 u = *(const float4*)(du + (size_t)gr * 128 + c4 * 4);
                v.x = (u.x >= 0.5f) ? 2.f * fmaxf(v.x, 0.f) : 0.f;
                v.y = (u.y >= 0.5f) ? 2.f * fmaxf(v.y, 0.f) : 0.f;
                v.z = (u.z >= 0.5f) ? 2.f * fmaxf(v.z, 0.f) : 0.f;
                v.w = (u.w >= 0.5f) ? 2.f * fmaxf(v.w, 0.f) : 0.f;
            }
        }
        ushort4 b;
        b.x = f2bf(v.x); b.y = f2bf(v.y); b.z = f2bf(v.z); b.w = f2bf(v.w);
        *(ushort4*)(&As[r * KP + c4 * 4]) = b;
    }
    for (int f = tid; f < 32 * NCOL; f += 256) {
        int k = f / (NCOL / 4), n4 = f % (NCOL / 4);
        float4 v = *(const float4*)(W + (size_t)k * NCOL + n4 * 4);
        Wt[(n4 * 4 + 0) * KP + k] = f2bf(v.x);
        Wt[(n4 * 4 + 1) * KP + k] = f2bf(v.y);
        Wt[(n4 * 4 + 2) * KP + k] = f2bf(v.z);
        Wt[(n4 * 4 + 3) * KP + k] = f2bf(v.w);
    }
    __syncthreads();

    const int wave = tid >> 6, lane = tid & 63;
    const int quad = lane >> 4, l16 = lane & 15;
    constexpr int CT = (NCOL == 128) ? 2 : 1;
    const int col0 = wave * 16 * CT;

    f32x4 acc[4][CT];
#pragma unroll
    for (int rt = 0; rt < 4; ++rt)
#pragma unroll
        for (int ct = 0; ct < CT; ++ct) acc[rt][ct] = 0.f;

#pragma unroll
    for (int ks = 0; ks < 4; ++ks) {
        const int kbase = ks * 32 + quad * 8;
        bf16x8 bfr[CT];
#pragma unroll
        for (int ct = 0; ct < CT; ++ct)
            bfr[ct] = *(const bf16x8*)(&Wt[(col0 + ct * 16 + l16) * KP + kbase]);
#pragma unroll
        for (int rt = 0; rt < 4; ++rt) {
            bf16x8 afr = *(const bf16x8*)(&As[(rt * 16 + l16) * KP + kbase]);
#pragma unroll
            for (int ct = 0; ct < CT; ++ct)
                acc[rt][ct] = __builtin_amdgcn_mfma_f32_16x16x32_bf16(afr, bfr[ct], acc[rt][ct], 0, 0, 0);
        }
    }

#pragma unroll
    for (int rt = 0; rt < 4; ++rt)
#pragma unroll
        for (int ct = 0; ct < CT; ++ct) {
            const int c = col0 + ct * 16 + l16;
            const float bv = bias ? bias[c] : 0.f;
#pragma unroll
            for (int reg = 0; reg < 4; ++reg) {
                const int gr = row0 + rt * 16 + quad * 4 + reg;
                if (gr < M) out[(size_t)gr * NCOL + c] = f2bf(acc[rt][ct][reg] + bv);
            }
        }
}

// ---------- CSR gather (bf16 input rows, fp32 accumulate+output) ----------
__device__ __forceinline__ void bfacc(uint4 v, float d, float* acc) {
    acc[0] = fmaf(d, __uint_as_float(v.x << 16),        acc[0]);
    acc[1] = fmaf(d, __uint_as_float(v.x & 0xffff0000u), acc[1]);
    acc[2] = fmaf(d, __uint_as_float(v.y << 16),        acc[2]);
    acc[3] = fmaf(d, __uint_as_float(v.y & 0xffff0000u), acc[3]);
    acc[4] = fmaf(d, __uint_as_float(v.z << 16),        acc[4]);
    acc[5] = fmaf(d, __uint_as_float(v.z & 0xffff0000u), acc[5]);
    acc[6] = fmaf(d, __uint_as_float(v.w << 16),        acc[6]);
    acc[7] = fmaf(d, __uint_as_float(v.w & 0xffff0000u), acc[7]);
}

template <int NCOL>
__global__ __launch_bounds__(256) void k_gather(const unsigned short* __restrict__ h,
                                                const int* __restrict__ row_start,
                                                const int* __restrict__ col,
                                                const float* __restrict__ dis,
                                                const float* __restrict__ bias,
                                                float* __restrict__ out, int n) {
    constexpr int LPN = NCOL / 8;
    const int node = (blockIdx.x * 256 + threadIdx.x) / LPN;
    const int l = threadIdx.x % LPN;
    if (node >= n) return;
    const int coff = l * 8;

    const float dn = dis[node];
    float acc[8];
    {
        uint4 v = *(const uint4*)(h + (size_t)node * NCOL + coff);
#pragma unroll
        for (int q = 0; q < 8; ++q) acc[q] = 0.f;
        bfacc(v, dn, acc);
    }

    const int beg = row_start[node], end = row_start[node + 1];
    int j = beg;
    for (; j + 1 < end; j += 2) {
        const int s0 = col[j], s1 = col[j + 1];
        const float d0 = dis[s0], d1 = dis[s1];
        const uint4 v0 = *(const uint4*)(h + (size_t)s0 * NCOL + coff);
        const uint4 v1 = *(const uint4*)(h + (size_t)s1 * NCOL + coff);
        bfacc(v0, d0, acc);
        bfacc(v1, d1, acc);
    }
    if (j < end) {
        const int s0 = col[j];
        const float d0 = dis[s0];
        const uint4 v0 = *(const uint4*)(h + (size_t)s0 * NCOL + coff);
        bfacc(v0, d0, acc);
    }

    float4 r0, r1;
    const float4 b0 = *(const float4*)(bias + coff);
    const float4 b1 = *(const float4*)(bias + coff + 4);
    r0.x = fmaf(dn, acc[0], b0.x); r0.y = fmaf(dn, acc[1], b0.y);
    r0.z = fmaf(dn, acc[2], b0.z); r0.w = fmaf(dn, acc[3], b0.w);
    r1.x = fmaf(dn, acc[4], b1.x); r1.y = fmaf(dn, acc[5], b1.y);
    r1.z = fmaf(dn, acc[6], b1.z); r1.w = fmaf(dn, acc[7], b1.w);
    float* o = out + (size_t)node * NCOL + coff;
    *(float4*)(o) = r0;
    *(float4*)(o + 4) = r1;
}

// ---------- pooling: sorted-batch sequential accumulation, wide grid ----------
__global__ __launch_bounds__(256) void k_pool(const float* __restrict__ h,
                                              const int* __restrict__ batch,
                                              float* __restrict__ sums,
                                              float* __restrict__ cnt,
                                              int n) {
    int gid = (blockIdx.x * 256 + threadIdx.x) / 64;
    int f = threadIdx.x % 64;
    int ngroups = gridDim.x * 4;
    int per = (n + ngroups - 1) / ngroups;
    int start = gid * per;
    int end = min(n, start + per);
    if (start >= end) return;
    int cg = batch[start];
    float acc = 0.f;
    int count = 0;
    for (int i = start; i < end; ++i) {
        int b = batch[i];
        if (b != cg) {
            atomAddF(&sums[cg * 64 + f], acc);
            if (f == 0) atomAddF(&cnt[cg], (float)count);
            acc = 0.f; count = 0; cg = b;
        }
        acc += h[(size_t)i * 64 + f];
        ++count;
    }
    atomAddF(&sums[cg * 64 + f], acc);
    if (f == 0) atomAddF(&cnt[cg], (float)count);
}

// ---------- final ----------
__global__ __launch_bounds__(64) void k_final(const float* __restrict__ sums,
                                              const float* __restrict__ cnt,
                                              const float* __restrict__ w,
                                              const float* __restrict__ b,
                                              float* __restrict__ out) {
    int g = blockIdx.x, f = threadIdx.x;
    float c = fmaxf(cnt[g], 1.0f);
    float p = sums[g * 64 + f] / c;
#pragma unroll
    for (int cls = 0; cls < NCLS; ++cls) {
        float v = p * w[f * 10 + cls];
#pragma unroll
        for (int o = 32; o > 0; o >>= 1) v += __shfl_down(v, o);
        if (f == 0) out[g * 10 + cls] = v + b[cls];
    }
}

extern "C" void kernel_launch(void* const* d_in, const int* in_sizes, int n_in,
                              void* d_out, int out_size, void* d_ws, size_t ws_size,
                              hipStream_t stream) {
    const float* x       = (const float*)d_in[0];
    const int*   ei      = (const int*)d_in[1];
    const int*   batch   = (const int*)d_in[2];
    const float* drop_u  = (const float*)d_in[4];
    const float* lin1_w  = (const float*)d_in[5];
    const float* lin1_b  = (const float*)d_in[6];
    const float* conv1_w = (const float*)d_in[7];
    const float* conv1_b = (const float*)d_in[8];
    const float* conv2_w = (const float*)d_in[9];
    const float* conv2_b = (const float*)d_in[10];
    const float* lin2_w  = (const float*)d_in[11];
    const float* lin2_b  = (const float*)d_in[12];
    float* out = (float*)d_out;

    const int N = in_sizes[0] / DIN;        // 100000
    const int E = in_sizes[1] / 2;          // 1600000
    const int* src = ei;
    const int* dst = ei + E;

    const int nbkt = (N + 255) >> 8;        // 391
    const int M = nbkt * NBLK;              // bh scan length

    // workspace layout (float units; int regions padded to even counts)
    float* ws    = (float*)d_ws;
    float* out1  = ws;                                   // N*128 fp32 (reused as out2)
    unsigned short* h1b = (unsigned short*)(ws + (size_t)N * 128);   // N*128 bf16 (reused as h2b)
    float* dis   = ws + (size_t)N * 128 + (size_t)N * 64;            // N
    float* W12   = dis + N;                              // 16384
    float* c1pb  = W12 + 16384;                          // 128
    float* sums  = c1pb + 128;                           // 8192
    float* cntp  = sums + NGRAPH * 64;                   // 128
    int*   row_start = (int*)(cntp + NGRAPH);            // N+2 (padded)
    int*   part  = row_start + N + 2;                    // 256
    int*   bh    = part + 256;                           // NBKT_MAX*NBLK+2
    int*   col   = bh + NBKT_MAX * NBLK + 2;             // E
    int2*  pairs = (int2*)(col + E);                     // E int2
    unsigned short* h2b = h1b;
    float* out2  = out1;

    // fused weight + pre-aggregation bias
    k_w12<<<129, 128, 0, stream>>>(lin1_w, lin1_b, conv1_w, W12, c1pb);

    // radix CSR build: hist -> scan(in-place) -> partition -> per-bucket LDS CSR
    k_bhist<<<NBLK, 256, 0, stream>>>(dst, bh, E, nbkt);
    const int scanB = (M + SCAN_CHUNK - 1) / SCAN_CHUNK;          // 98 <= 256
    k_scan_part<<<scanB, 256, 0, stream>>>(bh, part, M);
    k_scan_mid<<<1, 256, 0, stream>>>(part, bh, scanB, M);        // also bh[M] = E
    k_scan_fin2<<<scanB, 256, 0, stream>>>(bh, part, bh, M);
    k_partition<<<NBLK, 256, 0, stream>>>(src, dst, bh, pairs, E, nbkt);
    k_csr_local<<<nbkt, 256, 0, stream>>>(pairs, bh, row_start, dis, col, N);

    // h1b = bf16(x @ W12 + c1pb)   (MFMA)
    const int gemmGrid = (N + 63) / 64;
    k_gemm_mfma<128, false><<<gemmGrid, 256, 0, stream>>>(x, W12, c1pb, nullptr, h1b, N);

    // conv1 aggregation: out1 = fp32 gather of bf16 h1b
    k_gather<128><<<((size_t)N * 16 + 255) / 256, 256, 0, stream>>>(h1b, row_start, col, dis, conv1_b, out1, N);

    // h2b = bf16(relu(dropout(out1)) @ conv2_w)   (MFMA)
    k_gemm_mfma<64, true><<<gemmGrid, 256, 0, stream>>>(out1, conv2_w, nullptr, drop_u, h2b, N);

    // conv2 aggregation: out2 = fp32 gather of bf16 h2b
    k_gather<64><<<((size_t)N * 8 + 255) / 256, 256, 0, stream>>>(h2b, row_start, col, dis, conv2_b, out2, N);

    // pooled mean + classifier
    k_zero<<<(NGRAPH * 64 + NGRAPH + 255) / 256, 256, 0, stream>>>(sums, NGRAPH * 64 + NGRAPH);
    k_pool<<<2048, 256, 0, stream>>>(out2, batch, sums, cntp, N);
    k_final<<<NGRAPH, 64, 0, stream>>>(sums, cntp, lin2_w, lin2_b, out);
}